// Round 2
// baseline (110.133 us; speedup 1.0000x reference)
//
#include <hip/hip_runtime.h>

typedef unsigned int u32;

// ---------------- FFT-based reverb (R18: fuse kD+kE via all-resident spin) ----------------
// out[t] = sum_k audio[t+k] ir[k], t in [0,480000); M = 2^20 circular == linear.
// z = a + i*b ; Z1 = F[z]; A=(Z1[f]+conj(Z1[M-f]))/2, B=(Z1[f]-conj(Z1[M-f]))/(2i)
// X = S = A*conj(B)  (Hermitian). y = IDFT_M(X) real.
// Real-IFFT trick: w[p] = y[2p]+i*y[2p+1]; Z[k] = A_k + B_k, k<N2=M/2:
//   A_k = (X[k]+conj(X[N2-k]))/2,  B_k = (i/2)*conj(W_M^k)*(X[k]-conj(X[N2-k]))
//   w = IDFT_N2(Z) = conj(FFT_N2(conj(Z)/N2)); y[2p]=Re W'[p], y[2p+1]=-Im W'[p].
// Four-step T1: M=1024x1024 (verified R8-R17). Transform-2': N2 = 512(a) x 1024(b).
// R12 lesson: no grid.sync on MI355X.
// R17 lesson: occupancy is a dead lever — kernels are per-CU-throughput bound;
//   dur_us is dominated by ~87us of harness workspace-poison fills. Remaining
//   budget is ~12us of kernels + inter-dispatch gaps.
// R18: kD fused with kE. kD uses col PAIRS {2q,2q+1} (grid 256 = 1 block/CU, all
//   resident by construction -> spin on a device counter is deadlock-free).
//   W' stays in registers; after global absmax is complete, each block writes
//   normalized output directly as float4 (4 consecutive floats per k2).
//   Removes: 1 dispatch (+tail), 8 MB rawT2 round-trip, the transpose kernel.

constexpr int N_AUDIO = 480000;
constexpr int M_FFT   = 1048576;      // 2^20

constexpr size_t OFF_C0   = 0;                    // 8 MB float2
constexpr size_t OFF_C1   = (size_t)M_FFT * 8;    // 8 MB float2
constexpr size_t OFF_SLOT = OFF_C1 + (size_t)M_FFT * 8;   // u32 absmax bits
constexpr size_t OFF_CNT  = OFF_SLOT + 4;                 // u32 done-counter

#define SW(i) ((i) + ((i) >> 4))      // LDS pad swizzle
constexpr int LSZ = 1088;             // SW(1023)=1086

// ---- compile-time twiddle ROM (constexpr Taylor, double precision) ----
struct F2 { float x, y; };
constexpr double D_PI = 3.14159265358979323846264338327950288;
constexpr double tay_sin(double x) {
    double t = x, s = x, x2 = x * x;
    for (int k = 1; k <= 11; ++k) { t *= -x2 / (double)((2 * k) * (2 * k + 1)); s += t; }
    return s;
}
constexpr double tay_cos(double x) {
    double t = 1.0, s = 1.0, x2 = x * x;
    for (int k = 1; k <= 11; ++k) { t *= -x2 / (double)((2 * k - 1) * (2 * k)); s += t; }
    return s;
}
struct Tab { F2 v[1024]; };
constexpr Tab make_t1() {   // W_1024^j, arg centered to [-pi,pi)
    Tab tb{};
    for (int j = 0; j < 1024; ++j) {
        int jj = (j < 512) ? j : j - 1024;
        double a = -2.0 * D_PI * (double)jj / 1024.0;
        tb.v[j] = F2{(float)tay_cos(a), (float)tay_sin(a)};
    }
    return tb;
}
constexpr Tab make_t2() {   // W_M^j
    Tab tb{};
    for (int j = 0; j < 1024; ++j) {
        double a = -2.0 * D_PI * (double)j / 1048576.0;
        tb.v[j] = F2{(float)tay_cos(a), (float)tay_sin(a)};
    }
    return tb;
}
__device__ constexpr Tab ROM_T1 = make_t1();
__device__ constexpr Tab ROM_T2 = make_t2();

__device__ __forceinline__ float2 ldrom(const Tab& tb, int i) {
    F2 f = tb.v[i];
    return make_float2(f.x, f.y);
}
__device__ __forceinline__ float2 cmul(float2 a, float2 b) {
    return make_float2(a.x * b.x - a.y * b.y, a.x * b.y + a.y * b.x);
}
__device__ __forceinline__ void stage_tabs(float2* lt1, float2* lt2, int t) {
    #pragma unroll
    for (int q = 0; q < 4; ++q) {
        int i = t + 256 * q;
        lt1[i] = ldrom(ROM_T1, i);
        lt2[i] = ldrom(ROM_T2, i);
    }
}

// Radix-4 Stockham FFT-1024, R rows, 256 threads, 5 stages, result in B0.
// (validated R10-R17 at R=2; R=1 identical code with shorter row loop)
template<int R>
__device__ __forceinline__ void fft1024_r4(float2 (*A0)[LSZ], float2 (*B0)[LSZ],
                                           const float2* lt1, int t) {
    float2 (*A)[LSZ] = A0;
    float2 (*B)[LSZ] = B0;
    #pragma unroll
    for (int s = 0; s < 5; ++s) {
        const int L  = 1 << (2 * s);
        const int k  = t & (L - 1);
        const int p0 = 4 * t - 3 * k;
        const float2 w  = lt1[k << (9 - 2 * s)];   // e^{-2pi i k/(2L)}
        const float2 w2 = lt1[k << (8 - 2 * s)];   // e^{-2pi i k/(4L)}
        #pragma unroll
        for (int j = 0; j < R; ++j) {
            float2 x0 = A[j][SW(t)];
            float2 x2 = A[j][SW(t + 256)];
            float2 x1 = A[j][SW(t + 512)];
            float2 x3 = A[j][SW(t + 768)];
            float2 wx1 = cmul(w, x1), wx3 = cmul(w, x3);
            float2 u0 = make_float2(x0.x + wx1.x, x0.y + wx1.y);
            float2 u1 = make_float2(x0.x - wx1.x, x0.y - wx1.y);
            float2 u2 = make_float2(x2.x + wx3.x, x2.y + wx3.y);
            float2 u3 = make_float2(x2.x - wx3.x, x2.y - wx3.y);
            float2 a2 = cmul(w2, u2);
            float2 a3 = cmul(w2, u3);
            B[j][SW(p0)]         = make_float2(u0.x + a2.x, u0.y + a2.y);
            B[j][SW(p0 + L)]     = make_float2(u1.x + a3.y, u1.y - a3.x); // u1 - i*a3
            B[j][SW(p0 + 2*L)]   = make_float2(u0.x - a2.x, u0.y - a2.y);
            B[j][SW(p0 + 3*L)]   = make_float2(u1.x - a3.y, u1.y + a3.x); // u1 + i*a3
        }
        __syncthreads();
        float2 (*tmp)[LSZ] = A; A = B; B = tmp;
    }
}

// Radix-4x4 + radix-2 Stockham FFT-512 on TWO independent 512-pt arrays.
// 256 threads: col j = t>>7, tt = t&127. Result in B0. (validated R10-R17)
__device__ __forceinline__ void fft512_r4(float2 (*A0)[LSZ], float2 (*B0)[LSZ],
                                          const float2* lt1, int t) {
    float2 (*A)[LSZ] = A0;
    float2 (*B)[LSZ] = B0;
    const int j  = t >> 7;
    const int tt = t & 127;
    #pragma unroll
    for (int s = 0; s < 4; ++s) {
        const int L  = 1 << (2 * s);
        const int k  = tt & (L - 1);
        const int p0 = 4 * tt - 3 * k;
        const float2 w  = lt1[k << (9 - 2 * s)];
        const float2 w2 = lt1[k << (8 - 2 * s)];
        float2 x0 = A[j][SW(tt)];
        float2 x2 = A[j][SW(tt + 128)];
        float2 x1 = A[j][SW(tt + 256)];
        float2 x3 = A[j][SW(tt + 384)];
        float2 wx1 = cmul(w, x1), wx3 = cmul(w, x3);
        float2 u0 = make_float2(x0.x + wx1.x, x0.y + wx1.y);
        float2 u1 = make_float2(x0.x - wx1.x, x0.y - wx1.y);
        float2 u2 = make_float2(x2.x + wx3.x, x2.y + wx3.y);
        float2 u3 = make_float2(x2.x - wx3.x, x2.y - wx3.y);
        float2 a2 = cmul(w2, u2);
        float2 a3 = cmul(w2, u3);
        B[j][SW(p0)]       = make_float2(u0.x + a2.x, u0.y + a2.y);
        B[j][SW(p0 + L)]   = make_float2(u1.x + a3.y, u1.y - a3.x);
        B[j][SW(p0 + 2*L)] = make_float2(u0.x - a2.x, u0.y - a2.y);
        B[j][SW(p0 + 3*L)] = make_float2(u1.x - a3.y, u1.y + a3.x);
        __syncthreads();
        float2 (*tmp)[LSZ] = A; A = B; B = tmp;
    }
    // final radix-2 stage, L=256: 256 butterflies/col, 2 per thread
    #pragma unroll
    for (int h = 0; h < 2; ++h) {
        int i = tt + 128 * h;                   // 0..255, k = i
        float2 x0 = A[j][SW(i)];
        float2 x1 = A[j][SW(i + 256)];
        float2 w  = lt1[i << 1];                // e^{-2pi i i/512}
        float2 wx = cmul(w, x1);
        B[j][SW(i)]       = make_float2(x0.x + wx.x, x0.y + wx.y);
        B[j][SW(i + 256)] = make_float2(x0.x - wx.x, x0.y - wx.y);
    }
    __syncthreads();
}

// ---- kernel A: transform-1 pass1 + input pack. 1 row/block, grid 1024.
__global__ __launch_bounds__(256) void kA(const float* __restrict__ a,
                                          const float* __restrict__ b,
                                          float2* __restrict__ outb,
                                          u32* __restrict__ slot,
                                          u32* __restrict__ cnt) {
    __shared__ float2 buf0[1][LSZ], buf1[1][LSZ], lt1[1024], lt2[1024];
    const int t = threadIdx.x;
    const int r = blockIdx.x;
    if (r == 0 && t == 0) { *slot = 0u; *cnt = 0u; }
    stage_tabs(lt1, lt2, t);
    #pragma unroll
    for (int q = 0; q < 4; ++q) {
        int c = t + 256 * q;
        int base = c * 1024 + r;
        float av = 0.f, bv = 0.f;
        if (c < 468 || (c == 468 && r < 768)) av = a[base];   // 468*1024+768 = 480000
        if (c < 234 || (c == 234 && r < 384)) bv = b[base];   // 234*1024+384 = 240000
        buf0[0][SW(c)] = make_float2(av, bv);                 // z = a + i*b
    }
    __syncthreads();
    fft1024_r4<1>(buf0, buf1, lt1, t);
    #pragma unroll
    for (int q = 0; q < 4; ++q) {
        int k1 = t + 256 * q;
        int e = r * k1;                               // < 2^20
        float2 w = cmul(lt1[e >> 10], lt2[e & 1023]); // W_M^e
        outb[r * 1024 + k1] = cmul(w, buf1[0][SW(k1)]);
    }
}

// ---- kernel BC: T1 pass2 + pointwise + real-IFFT pack + T2' pass1 (FFT_512). grid 512.
// Block bidx owns Hermitian col pair {cA,cB} = {bidx, 1024-bidx} ({0,512} for 0).
// (unchanged — verified R16/R17.)
__global__ __launch_bounds__(256) void kBC(const float2* __restrict__ in,
                                           float2* __restrict__ gbuf) {
    __shared__ float2 buf0[2][LSZ], buf1[2][LSZ], lt1[1024], lt2[1024];
    const int t = threadIdx.x;
    const int bidx = blockIdx.x;
    const int cA = (bidx == 0) ? 0   : bidx;
    const int cB = (bidx == 0) ? 512 : 1024 - bidx;
    stage_tabs(lt1, lt2, t);
    #pragma unroll
    for (int q = 0; q < 4; ++q) {
        int r = t + 256 * q;
        buf0[0][SW(r)] = in[r * 1024 + cA];
        buf0[1][SW(r)] = in[r * 1024 + cB];
    }
    __syncthreads();
    fft1024_r4<2>(buf0, buf1, lt1, t);                // Z1 cols in buf1
    // pointwise: X = S_raw = A*conj(B), write to buf0 (reads buf1 only)
    #pragma unroll
    for (int q = 0; q < 4; ++q) {
        int k2 = t + 256 * q;
        #pragma unroll
        for (int j = 0; j < 2; ++j) {
            float2 z1 = buf1[j][SW(k2)];
            float2 z2;
            if (bidx == 0) z2 = (j == 0) ? buf1[0][SW((1024 - k2) & 1023)]
                                         : buf1[1][SW(1023 - k2)];
            else           z2 = buf1[j ^ 1][SW(1023 - k2)];
            float2 Af  = make_float2(0.5f * (z1.x + z2.x), 0.5f * (z1.y - z2.y));
            float2 cBf = make_float2(0.5f * (z1.y + z2.y), 0.5f * (z1.x - z2.x));
            buf0[j][SW(k2)] = cmul(Af, cBf);              // X (no scale, no conj)
        }
    }
    __syncthreads();
    // real-IFFT pack: q[k] = conj(Z[k])/N2 into buf1[j][0..511], k = b_j + 1024*k2v
    const float invN2 = 1.0f / 524288.0f;
    #pragma unroll
    for (int j = 0; j < 2; ++j) {
        const int bcol = (j == 0) ? cA : cB;
        const float2 wb = lt2[bcol];                      // W_M^{bcol}
        #pragma unroll
        for (int h = 0; h < 2; ++h) {
            int k2v = t + 256 * h;                        // 0..511
            float2 z1 = buf0[j][SW(k2v)];                 // X[k]
            int jr, p2;
            if (bidx == 0) { jr = j; p2 = (j == 0) ? (512 - k2v) : (511 - k2v); }
            else           { jr = j ^ 1; p2 = 511 - k2v; }
            float2 z2c = buf0[jr][SW(p2)];                // X[N2-k]
            z2c.y = -z2c.y;                               // conj
            float2 A2 = make_float2(0.5f * (z1.x + z2c.x), 0.5f * (z1.y + z2c.y));
            float2 D2 = make_float2(0.5f * (z1.x - z2c.x), 0.5f * (z1.y - z2c.y));
            float2 cw = cmul(lt1[k2v], wb);               // W_M^k
            float2 iB = cmul(make_float2(cw.y, cw.x), D2);// i*conj(cw)*D
            float2 Z  = make_float2(A2.x + iB.x, A2.y + iB.y);
            buf1[j][SW(k2v)] = make_float2(Z.x * invN2, -Z.y * invN2);  // conj(Z)/N2
        }
    }
    __syncthreads();
    fft512_r4(buf1, buf0, lt1, t);                        // G in buf0[j][0..511]
    // twiddle W_N2^{b*k1} = W_M^{2*b*k1}, store gbuf[b*512 + k1]
    const int jc = t >> 7, tt = t & 127;
    const int bcol = (jc == 0) ? cA : cB;
    #pragma unroll
    for (int u = 0; u < 4; ++u) {
        int k1 = tt + 128 * u;                            // 0..511
        int e2 = 2 * bcol * k1;                           // <= 1045506 < 2^20
        float2 w = cmul(lt1[e2 >> 10], lt2[e2 & 1023]);
        gbuf[bcol * 512 + k1] = cmul(w, buf0[jc][SW(k1)]);
    }
}

// ---- kernel D (fused with normalize): T2' pass2 + absmax + spin + direct output.
// Col pair {2qb, 2qb+1} per block, grid 256 = 1 block/CU; capacity is >=2 blocks/CU
// (42.8 KB LDS), so all 256 blocks are dispatched immediately -> spin is safe.
// W' kept in registers across the wait; output written as normalized float4:
// out[1024*k2 + 4*qb + {0..3}] = {Re W'_0, -Im W'_0, Re W'_1, -Im W'_1} * inv.
__global__ __launch_bounds__(256) void kD(const float2* __restrict__ gbuf,
                                          u32* __restrict__ slot,
                                          u32* __restrict__ cnt,
                                          float* __restrict__ out) {
    __shared__ float2 buf0[2][LSZ], buf1[2][LSZ], lt1[1024];
    __shared__ float wmax[4];
    __shared__ float s_inv;
    const int t = threadIdx.x;
    const int qb = blockIdx.x;                            // k1' = 2qb, 2qb+1
    #pragma unroll
    for (int q = 0; q < 4; ++q) { int i = t + 256 * q; lt1[i] = ldrom(ROM_T1, i); }
    #pragma unroll
    for (int q = 0; q < 4; ++q) {
        int b = t + 256 * q;
        float4 v = *(const float4*)(gbuf + (size_t)b * 512 + 2 * qb);
        buf0[0][SW(b)] = make_float2(v.x, v.y);
        buf0[1][SW(b)] = make_float2(v.z, v.w);
    }
    __syncthreads();
    fft1024_r4<2>(buf0, buf1, lt1, t);                    // W' in buf1
    // pull results into registers + masked abs-max (out length 480000 = 4*(1024*117+192))
    float2 r0[4], r1[4];
    float m = 0.0f;
    #pragma unroll
    for (int q = 0; q < 4; ++q) {
        int k2 = t + 256 * q;
        r0[q] = buf1[0][SW(k2)];
        r1[q] = buf1[1][SW(k2)];
        if (k2 < 468 || (k2 == 468 && qb < 192)) {        // all 4 outputs < N_AUDIO
            m = fmaxf(m, fmaxf(fabsf(r0[q].x), fabsf(r0[q].y)));
            m = fmaxf(m, fmaxf(fabsf(r1[q].x), fabsf(r1[q].y)));
        }
    }
    for (int off = 32; off > 0; off >>= 1) m = fmaxf(m, __shfl_down(m, off, 64));
    if ((t & 63) == 0) wmax[t >> 6] = m;
    __syncthreads();
    if (t == 0) {
        float bm = fmaxf(fmaxf(wmax[0], wmax[1]), fmaxf(wmax[2], wmax[3]));
        atomicMax(slot, __float_as_uint(bm));
        __threadfence();                                  // publish max before count
        atomicAdd(cnt, 1u);
        while (atomicAdd(cnt, 0u) < 256u) {               // device-scope coherent read
            __builtin_amdgcn_s_sleep(2);
        }
        __threadfence();                                  // acquire
        s_inv = 1.0f / __uint_as_float(atomicAdd(slot, 0u));
    }
    __syncthreads();
    const float inv = s_inv;
    #pragma unroll
    for (int q = 0; q < 4; ++q) {
        int k2 = t + 256 * q;
        if (k2 < 468 || (k2 == 468 && qb < 192)) {
            float4 o = make_float4(r0[q].x * inv, -r0[q].y * inv,
                                   r1[q].x * inv, -r1[q].y * inv);
            *(float4*)(out + 1024 * k2 + 4 * qb) = o;
        }
    }
}

extern "C" void kernel_launch(void* const* d_in, const int* in_sizes, int n_in,
                              void* d_out, int out_size, void* d_ws, size_t ws_size,
                              hipStream_t stream) {
    const float* audio = (const float*)d_in[0];
    const float* ir    = (const float*)d_in[1];
    float* out = (float*)d_out;

    char* ws = (char*)d_ws;
    float2* cb0 = (float2*)(ws + OFF_C0);
    float2* cb1 = (float2*)(ws + OFF_C1);
    u32*    slot = (u32*)(ws + OFF_SLOT);
    u32*    cnt  = (u32*)(ws + OFF_CNT);

    kA<<<1024, 256, 0, stream>>>(audio, ir, cb1, slot, cnt);    // pack + T1 rows
    kBC<<<512, 256, 0, stream>>>(cb1, cb0);                     // T1 cols + pw + pack + T2' rows
    kD<<<256, 256, 0, stream>>>(cb0, slot, cnt, out);           // T2' cols + absmax + spin + out
}

// Round 3
// 98.602 us; speedup vs baseline: 1.1169x; 1.1169x over previous
//
#include <hip/hip_runtime.h>

typedef unsigned int u32;

// ---------------- FFT-based reverb (R19: revert spin; kD writes out directly + tiny kN) ----------------
// out[t] = sum_k audio[t+k] ir[k], t in [0,480000); M = 2^20 circular == linear.
// z = a + i*b ; Z1 = F[z]; A=(Z1[f]+conj(Z1[M-f]))/2, B=(Z1[f]-conj(Z1[M-f]))/(2i)
// X = S = A*conj(B)  (Hermitian). y = IDFT_M(X) real.
// Real-IFFT trick: w[p] = y[2p]+i*y[2p+1]; Z[k] = A_k + B_k, k<N2=M/2:
//   A_k = (X[k]+conj(X[N2-k]))/2,  B_k = (i/2)*conj(W_M^k)*(X[k]-conj(X[N2-k]))
//   w = IDFT_N2(Z) = conj(FFT_N2(conj(Z)/N2)); y[2p]=Re W'[p], y[2p+1]=-Im W'[p].
// Four-step T1: M=1024x1024 (verified R8-R18). Transform-2': N2 = 512(a) x 1024(b).
// Session ledger:
//   R12: no grid.sync on MI355X.
//   R17: occupancy is a dead lever — kernels are per-CU-throughput bound; dur_us
//        is dominated by ~87us of harness workspace-poison fills (2 x 43.5us,
//        256 MiB each at 77% HBM peak). Controllable budget ~12us.
//   R18: device-scope spin barrier costs ~+11us (cross-XCD atomic poll + max-over-
//        blocks serialization) — FAR worse than an extra dispatch. Never again.
//        BUT: direct-output write math from kD (float4, masked) is now VERIFIED.
//   R19: kD keeps R18's verified direct out-write (unnormalized) + absmax atomic;
//        new tiny kN does the in-place scale. Removes kE's 8MB rawT2 round-trip
//        and its LDS transpose; adds ~1us of uncoalesced-write amplification and
//        a ~1us elementwise dispatch. Expected net -1..-2.5us vs R17.

constexpr int N_AUDIO = 480000;
constexpr int M_FFT   = 1048576;      // 2^20

constexpr size_t OFF_C0   = 0;                    // 8 MB float2
constexpr size_t OFF_C1   = (size_t)M_FFT * 8;    // 8 MB float2
constexpr size_t OFF_SLOT = OFF_C1 + (size_t)M_FFT * 8;   // u32 absmax bits

#define SW(i) ((i) + ((i) >> 4))      // LDS pad swizzle
constexpr int LSZ = 1088;             // SW(1023)=1086

// ---- compile-time twiddle ROM (constexpr Taylor, double precision) ----
struct F2 { float x, y; };
constexpr double D_PI = 3.14159265358979323846264338327950288;
constexpr double tay_sin(double x) {
    double t = x, s = x, x2 = x * x;
    for (int k = 1; k <= 11; ++k) { t *= -x2 / (double)((2 * k) * (2 * k + 1)); s += t; }
    return s;
}
constexpr double tay_cos(double x) {
    double t = 1.0, s = 1.0, x2 = x * x;
    for (int k = 1; k <= 11; ++k) { t *= -x2 / (double)((2 * k - 1) * (2 * k)); s += t; }
    return s;
}
struct Tab { F2 v[1024]; };
constexpr Tab make_t1() {   // W_1024^j, arg centered to [-pi,pi)
    Tab tb{};
    for (int j = 0; j < 1024; ++j) {
        int jj = (j < 512) ? j : j - 1024;
        double a = -2.0 * D_PI * (double)jj / 1024.0;
        tb.v[j] = F2{(float)tay_cos(a), (float)tay_sin(a)};
    }
    return tb;
}
constexpr Tab make_t2() {   // W_M^j
    Tab tb{};
    for (int j = 0; j < 1024; ++j) {
        double a = -2.0 * D_PI * (double)j / 1048576.0;
        tb.v[j] = F2{(float)tay_cos(a), (float)tay_sin(a)};
    }
    return tb;
}
__device__ constexpr Tab ROM_T1 = make_t1();
__device__ constexpr Tab ROM_T2 = make_t2();

__device__ __forceinline__ float2 ldrom(const Tab& tb, int i) {
    F2 f = tb.v[i];
    return make_float2(f.x, f.y);
}
__device__ __forceinline__ float2 cmul(float2 a, float2 b) {
    return make_float2(a.x * b.x - a.y * b.y, a.x * b.y + a.y * b.x);
}
__device__ __forceinline__ void stage_tabs(float2* lt1, float2* lt2, int t) {
    #pragma unroll
    for (int q = 0; q < 4; ++q) {
        int i = t + 256 * q;
        lt1[i] = ldrom(ROM_T1, i);
        lt2[i] = ldrom(ROM_T2, i);
    }
}

// Radix-4 Stockham FFT-1024, R rows, 256 threads, 5 stages, result in B0.
// (validated R10-R18 at R=1,2)
template<int R>
__device__ __forceinline__ void fft1024_r4(float2 (*A0)[LSZ], float2 (*B0)[LSZ],
                                           const float2* lt1, int t) {
    float2 (*A)[LSZ] = A0;
    float2 (*B)[LSZ] = B0;
    #pragma unroll
    for (int s = 0; s < 5; ++s) {
        const int L  = 1 << (2 * s);
        const int k  = t & (L - 1);
        const int p0 = 4 * t - 3 * k;
        const float2 w  = lt1[k << (9 - 2 * s)];   // e^{-2pi i k/(2L)}
        const float2 w2 = lt1[k << (8 - 2 * s)];   // e^{-2pi i k/(4L)}
        #pragma unroll
        for (int j = 0; j < R; ++j) {
            float2 x0 = A[j][SW(t)];
            float2 x2 = A[j][SW(t + 256)];
            float2 x1 = A[j][SW(t + 512)];
            float2 x3 = A[j][SW(t + 768)];
            float2 wx1 = cmul(w, x1), wx3 = cmul(w, x3);
            float2 u0 = make_float2(x0.x + wx1.x, x0.y + wx1.y);
            float2 u1 = make_float2(x0.x - wx1.x, x0.y - wx1.y);
            float2 u2 = make_float2(x2.x + wx3.x, x2.y + wx3.y);
            float2 u3 = make_float2(x2.x - wx3.x, x2.y - wx3.y);
            float2 a2 = cmul(w2, u2);
            float2 a3 = cmul(w2, u3);
            B[j][SW(p0)]         = make_float2(u0.x + a2.x, u0.y + a2.y);
            B[j][SW(p0 + L)]     = make_float2(u1.x + a3.y, u1.y - a3.x); // u1 - i*a3
            B[j][SW(p0 + 2*L)]   = make_float2(u0.x - a2.x, u0.y - a2.y);
            B[j][SW(p0 + 3*L)]   = make_float2(u1.x - a3.y, u1.y + a3.x); // u1 + i*a3
        }
        __syncthreads();
        float2 (*tmp)[LSZ] = A; A = B; B = tmp;
    }
}

// Radix-4x4 + radix-2 Stockham FFT-512 on TWO independent 512-pt arrays.
// 256 threads: col j = t>>7, tt = t&127. Result in B0. (validated R10-R18)
__device__ __forceinline__ void fft512_r4(float2 (*A0)[LSZ], float2 (*B0)[LSZ],
                                          const float2* lt1, int t) {
    float2 (*A)[LSZ] = A0;
    float2 (*B)[LSZ] = B0;
    const int j  = t >> 7;
    const int tt = t & 127;
    #pragma unroll
    for (int s = 0; s < 4; ++s) {
        const int L  = 1 << (2 * s);
        const int k  = tt & (L - 1);
        const int p0 = 4 * tt - 3 * k;
        const float2 w  = lt1[k << (9 - 2 * s)];
        const float2 w2 = lt1[k << (8 - 2 * s)];
        float2 x0 = A[j][SW(tt)];
        float2 x2 = A[j][SW(tt + 128)];
        float2 x1 = A[j][SW(tt + 256)];
        float2 x3 = A[j][SW(tt + 384)];
        float2 wx1 = cmul(w, x1), wx3 = cmul(w, x3);
        float2 u0 = make_float2(x0.x + wx1.x, x0.y + wx1.y);
        float2 u1 = make_float2(x0.x - wx1.x, x0.y - wx1.y);
        float2 u2 = make_float2(x2.x + wx3.x, x2.y + wx3.y);
        float2 u3 = make_float2(x2.x - wx3.x, x2.y - wx3.y);
        float2 a2 = cmul(w2, u2);
        float2 a3 = cmul(w2, u3);
        B[j][SW(p0)]       = make_float2(u0.x + a2.x, u0.y + a2.y);
        B[j][SW(p0 + L)]   = make_float2(u1.x + a3.y, u1.y - a3.x);
        B[j][SW(p0 + 2*L)] = make_float2(u0.x - a2.x, u0.y - a2.y);
        B[j][SW(p0 + 3*L)] = make_float2(u1.x - a3.y, u1.y + a3.x);
        __syncthreads();
        float2 (*tmp)[LSZ] = A; A = B; B = tmp;
    }
    // final radix-2 stage, L=256: 256 butterflies/col, 2 per thread
    #pragma unroll
    for (int h = 0; h < 2; ++h) {
        int i = tt + 128 * h;                   // 0..255, k = i
        float2 x0 = A[j][SW(i)];
        float2 x1 = A[j][SW(i + 256)];
        float2 w  = lt1[i << 1];                // e^{-2pi i i/512}
        float2 wx = cmul(w, x1);
        B[j][SW(i)]       = make_float2(x0.x + wx.x, x0.y + wx.y);
        B[j][SW(i + 256)] = make_float2(x0.x - wx.x, x0.y - wx.y);
    }
    __syncthreads();
}

// ---- kernel A: transform-1 pass1 + input pack. 1 row/block, grid 1024. (validated R17/R18)
__global__ __launch_bounds__(256) void kA(const float* __restrict__ a,
                                          const float* __restrict__ b,
                                          float2* __restrict__ outb,
                                          u32* __restrict__ slot) {
    __shared__ float2 buf0[1][LSZ], buf1[1][LSZ], lt1[1024], lt2[1024];
    const int t = threadIdx.x;
    const int r = blockIdx.x;
    if (r == 0 && t == 0) *slot = 0u;
    stage_tabs(lt1, lt2, t);
    #pragma unroll
    for (int q = 0; q < 4; ++q) {
        int c = t + 256 * q;
        int base = c * 1024 + r;
        float av = 0.f, bv = 0.f;
        if (c < 468 || (c == 468 && r < 768)) av = a[base];   // 468*1024+768 = 480000
        if (c < 234 || (c == 234 && r < 384)) bv = b[base];   // 234*1024+384 = 240000
        buf0[0][SW(c)] = make_float2(av, bv);                 // z = a + i*b
    }
    __syncthreads();
    fft1024_r4<1>(buf0, buf1, lt1, t);
    #pragma unroll
    for (int q = 0; q < 4; ++q) {
        int k1 = t + 256 * q;
        int e = r * k1;                               // < 2^20
        float2 w = cmul(lt1[e >> 10], lt2[e & 1023]); // W_M^e
        outb[r * 1024 + k1] = cmul(w, buf1[0][SW(k1)]);
    }
}

// ---- kernel BC: T1 pass2 + pointwise + real-IFFT pack + T2' pass1 (FFT_512). grid 512.
// Block bidx owns Hermitian col pair {cA,cB} = {bidx, 1024-bidx} ({0,512} for 0).
// (unchanged — verified R16-R18.)
__global__ __launch_bounds__(256) void kBC(const float2* __restrict__ in,
                                           float2* __restrict__ gbuf) {
    __shared__ float2 buf0[2][LSZ], buf1[2][LSZ], lt1[1024], lt2[1024];
    const int t = threadIdx.x;
    const int bidx = blockIdx.x;
    const int cA = (bidx == 0) ? 0   : bidx;
    const int cB = (bidx == 0) ? 512 : 1024 - bidx;
    stage_tabs(lt1, lt2, t);
    #pragma unroll
    for (int q = 0; q < 4; ++q) {
        int r = t + 256 * q;
        buf0[0][SW(r)] = in[r * 1024 + cA];
        buf0[1][SW(r)] = in[r * 1024 + cB];
    }
    __syncthreads();
    fft1024_r4<2>(buf0, buf1, lt1, t);                // Z1 cols in buf1
    // pointwise: X = S_raw = A*conj(B), write to buf0 (reads buf1 only)
    #pragma unroll
    for (int q = 0; q < 4; ++q) {
        int k2 = t + 256 * q;
        #pragma unroll
        for (int j = 0; j < 2; ++j) {
            float2 z1 = buf1[j][SW(k2)];
            float2 z2;
            if (bidx == 0) z2 = (j == 0) ? buf1[0][SW((1024 - k2) & 1023)]
                                         : buf1[1][SW(1023 - k2)];
            else           z2 = buf1[j ^ 1][SW(1023 - k2)];
            float2 Af  = make_float2(0.5f * (z1.x + z2.x), 0.5f * (z1.y - z2.y));
            float2 cBf = make_float2(0.5f * (z1.y + z2.y), 0.5f * (z1.x - z2.x));
            buf0[j][SW(k2)] = cmul(Af, cBf);              // X (no scale, no conj)
        }
    }
    __syncthreads();
    // real-IFFT pack: q[k] = conj(Z[k])/N2 into buf1[j][0..511], k = b_j + 1024*k2v
    const float invN2 = 1.0f / 524288.0f;
    #pragma unroll
    for (int j = 0; j < 2; ++j) {
        const int bcol = (j == 0) ? cA : cB;
        const float2 wb = lt2[bcol];                      // W_M^{bcol}
        #pragma unroll
        for (int h = 0; h < 2; ++h) {
            int k2v = t + 256 * h;                        // 0..511
            float2 z1 = buf0[j][SW(k2v)];                 // X[k]
            int jr, p2;
            if (bidx == 0) { jr = j; p2 = (j == 0) ? (512 - k2v) : (511 - k2v); }
            else           { jr = j ^ 1; p2 = 511 - k2v; }
            float2 z2c = buf0[jr][SW(p2)];                // X[N2-k]
            z2c.y = -z2c.y;                               // conj
            float2 A2 = make_float2(0.5f * (z1.x + z2c.x), 0.5f * (z1.y + z2c.y));
            float2 D2 = make_float2(0.5f * (z1.x - z2c.x), 0.5f * (z1.y - z2c.y));
            float2 cw = cmul(lt1[k2v], wb);               // W_M^k
            float2 iB = cmul(make_float2(cw.y, cw.x), D2);// i*conj(cw)*D
            float2 Z  = make_float2(A2.x + iB.x, A2.y + iB.y);
            buf1[j][SW(k2v)] = make_float2(Z.x * invN2, -Z.y * invN2);  // conj(Z)/N2
        }
    }
    __syncthreads();
    fft512_r4(buf1, buf0, lt1, t);                        // G in buf0[j][0..511]
    // twiddle W_N2^{b*k1} = W_M^{2*b*k1}, store gbuf[b*512 + k1]
    const int jc = t >> 7, tt = t & 127;
    const int bcol = (jc == 0) ? cA : cB;
    #pragma unroll
    for (int u = 0; u < 4; ++u) {
        int k1 = tt + 128 * u;                            // 0..511
        int e2 = 2 * bcol * k1;                           // <= 1045506 < 2^20
        float2 w = cmul(lt1[e2 >> 10], lt2[e2 & 1023]);
        gbuf[bcol * 512 + k1] = cmul(w, buf0[jc][SW(k1)]);
    }
}

// ---- kernel D: T2' pass2 (FFT_1024 over b), col pair {2qb,2qb+1}, grid 256.
// Writes UNNORMALIZED output directly (float4 per (k2,qb): out[1024*k2+4*qb+{0..3}]
// = {Re W'_0, -Im W'_0, Re W'_1, -Im W'_1}) + absmax atomic. Math verified in R18.
// No spin (R18 lesson) — the scale is applied by kN after this dispatch completes.
__global__ __launch_bounds__(256) void kD(const float2* __restrict__ gbuf,
                                          u32* __restrict__ slot,
                                          float* __restrict__ out) {
    __shared__ float2 buf0[2][LSZ], buf1[2][LSZ], lt1[1024];
    __shared__ float wmax[4];
    const int t = threadIdx.x;
    const int qb = blockIdx.x;                            // k1' = 2qb, 2qb+1
    #pragma unroll
    for (int q = 0; q < 4; ++q) { int i = t + 256 * q; lt1[i] = ldrom(ROM_T1, i); }
    #pragma unroll
    for (int q = 0; q < 4; ++q) {
        int b = t + 256 * q;
        float4 v = *(const float4*)(gbuf + (size_t)b * 512 + 2 * qb);
        buf0[0][SW(b)] = make_float2(v.x, v.y);
        buf0[1][SW(b)] = make_float2(v.z, v.w);
    }
    __syncthreads();
    fft1024_r4<2>(buf0, buf1, lt1, t);                    // W' in buf1
    float m = 0.0f;
    #pragma unroll
    for (int q = 0; q < 4; ++q) {
        int k2 = t + 256 * q;
        float2 v0 = buf1[0][SW(k2)];
        float2 v1 = buf1[1][SW(k2)];
        if (k2 < 468 || (k2 == 468 && qb < 192)) {        // all 4 outputs < N_AUDIO
            m = fmaxf(m, fmaxf(fabsf(v0.x), fabsf(v0.y)));
            m = fmaxf(m, fmaxf(fabsf(v1.x), fabsf(v1.y)));
            *(float4*)(out + 1024 * k2 + 4 * qb) =
                make_float4(v0.x, -v0.y, v1.x, -v1.y);    // unnormalized
        }
    }
    for (int off = 32; off > 0; off >>= 1) m = fmaxf(m, __shfl_down(m, off, 64));
    if ((t & 63) == 0) wmax[t >> 6] = m;
    __syncthreads();
    if (t == 0) {
        float bm = fmaxf(fmaxf(wmax[0], wmax[1]), fmaxf(wmax[2], wmax[3]));
        atomicMax(slot, __float_as_uint(bm));
    }
}

// ---- kernel N: in-place normalize. 480000 floats = 120000 float4s. grid 469.
__global__ __launch_bounds__(256) void kN(float* __restrict__ out,
                                          const u32* __restrict__ slot) {
    const int i = blockIdx.x * 256 + threadIdx.x;         // float4 index
    if (i < 120000) {
        const float inv = 1.0f / __uint_as_float(*slot);
        float4 v = *(float4*)(out + 4 * i);
        *(float4*)(out + 4 * i) = make_float4(v.x * inv, v.y * inv,
                                              v.z * inv, v.w * inv);
    }
}

extern "C" void kernel_launch(void* const* d_in, const int* in_sizes, int n_in,
                              void* d_out, int out_size, void* d_ws, size_t ws_size,
                              hipStream_t stream) {
    const float* audio = (const float*)d_in[0];
    const float* ir    = (const float*)d_in[1];
    float* out = (float*)d_out;

    char* ws = (char*)d_ws;
    float2* cb0 = (float2*)(ws + OFF_C0);
    float2* cb1 = (float2*)(ws + OFF_C1);
    u32*    slot = (u32*)(ws + OFF_SLOT);

    kA<<<1024, 256, 0, stream>>>(audio, ir, cb1, slot);   // pack + T1 rows
    kBC<<<512, 256, 0, stream>>>(cb1, cb0);               // T1 cols + pw + pack + T2' rows
    kD<<<256, 256, 0, stream>>>(cb0, slot, out);          // T2' cols + absmax + raw out
    kN<<<469, 256, 0, stream>>>(out, slot);               // in-place scale
}